// Round 5
// baseline (557.147 us; speedup 1.0000x reference)
//
#include <hip/hip_runtime.h>
#include <hip/hip_fp16.h>

typedef _Float16 half8 __attribute__((ext_vector_type(8)));
typedef float    floatx4 __attribute__((ext_vector_type(4)));

#define MFMA16(a, b, c) __builtin_amdgcn_mfma_f32_16x16x32_f16((a), (b), (c), 0, 0, 0)

constexpr int T_ = 2048;
constexpr int D_ = 1024;
constexpr int NB = 4;

__device__ __forceinline__ half8 cvt8(floatx4 a, floatx4 b) {
  half8 h;
  h[0] = (_Float16)a[0]; h[1] = (_Float16)a[1]; h[2] = (_Float16)a[2]; h[3] = (_Float16)a[3];
  h[4] = (_Float16)b[0]; h[5] = (_Float16)b[1]; h[6] = (_Float16)b[2]; h[7] = (_Float16)b[3];
  return h;
}

// ---- prep: cast V->f16 (Vh) and build transposed VhT[D][T] ----
template <int MODE>
__global__ __launch_bounds__(256) void prep(const float* __restrict__ V,
                                            _Float16* __restrict__ VhT,
                                            _Float16* __restrict__ Vh) {
  __shared__ _Float16 tile[64][65];
  const int bid = blockIdx.x;
  const int b = bid & 3;
  const int tt = (bid >> 2) & 31;
  const int dd = bid >> 7;
  const float* Vb = V + ((size_t)b * T_ + tt * 64) * D_ + dd * 64;
#pragma unroll
  for (int k = 0; k < 16; ++k) {
    const int e = k * 256 + threadIdx.x;
    const int r = e >> 6, c = e & 63;
    const _Float16 h = (_Float16)Vb[(size_t)r * D_ + c];
    tile[r][c] = h;
    if (MODE == 2) Vh[((size_t)b * T_ + tt * 64 + r) * D_ + dd * 64 + c] = h;
  }
  __syncthreads();
#pragma unroll
  for (int k = 0; k < 16; ++k) {
    const int e = k * 256 + threadIdx.x;
    const int dr = e >> 6, tc = e & 63;
    VhT[((size_t)b * D_ + dd * 64 + dr) * T_ + tt * 64 + tc] = tile[tc][dr];
  }
}

template <int MODE>
__device__ __forceinline__ half8 loadAg(const _Float16* __restrict__ Vhb,
                                        const float* __restrict__ Vb, int row, int col) {
  if (MODE == 2) return *(const half8*)(Vhb + (size_t)row * D_ + col);
  const float* p = Vb + (size_t)row * D_ + col;
  return cvt8(*(const floatx4*)p, *(const floatx4*)(p + 4));
}

template <int MODE>
__device__ __forceinline__ half8 loadBg(const _Float16* __restrict__ VhTb,
                                        const float* __restrict__ Vb, int dim, int kv) {
  if (MODE >= 1) return *(const half8*)(VhTb + (size_t)dim * T_ + kv);
  half8 h;
#pragma unroll
  for (int j = 0; j < 8; ++j) h[j] = (_Float16)Vb[(size_t)(kv + j) * D_ + dim];
  return h;
}

// ---- causal flash attention, K=V, Br=16, Bc=32, 3-stage pipelined steps ----
// step k: softmax(k) || PV(k-1) || QK(k+1)+loads(k+1,k+2); ONE barrier/step.
template <int MODE>
__global__ __launch_bounds__(512, 2) void attn(const float* __restrict__ Qg,
                                               const float* __restrict__ Vg,
                                               const _Float16* __restrict__ VhTg,
                                               const _Float16* __restrict__ Vhg,
                                               float* __restrict__ Og) {
  // RED[par][wave][16 q][32 kv] f32, XOR-swizzled by q
  __shared__ __align__(16) char REDb[2 * 8 * 16 * 32 * 4];   // 32 KB
  __shared__ __align__(16) char PLb[2 * 16 * 32 * 2];        // 2 KB, swizzled
  __shared__ float AL[2][16];
  __shared__ float Lsh[16];

  const int tid = threadIdx.x;
  const int w = tid >> 6, l = tid & 63, l15 = l & 15, hi = l >> 4;
  const int koff = hi * 8;
  const int row_sm = 2 * w + (l >> 5);   // softmax row owned by this lane
  const int kv_sm = l & 31;

  const int batch = (int)(blockIdx.x & 3);   // batch->XCD-pair affinity
  const int pp = (int)(blockIdx.x >> 2);     // 0..63

  const float* Qb = Qg + (size_t)batch * T_ * D_;
  const float* Vb = Vg + (size_t)batch * T_ * D_;
  const _Float16* VhTb = (MODE >= 1) ? VhTg + (size_t)batch * T_ * D_ : (const _Float16*)nullptr;
  const _Float16* Vhb  = (MODE == 2) ? Vhg  + (size_t)batch * T_ * D_ : (const _Float16*)nullptr;

  for (int it = 0; it < 2; ++it) {
    const int s = it ? pp : (127 - pp);      // balanced pair, long first
    const int qbase = s * 16;
    const int n = (qbase + 16 + 31) >> 5;    // # 32-kv tiles

    half8 qfrag[4];
#pragma unroll
    for (int c = 0; c < 4; ++c) {
      const float* p = Qb + (size_t)(qbase + l15) * D_ + w * 128 + c * 32 + koff;
      qfrag[c] = cvt8(*(const floatx4*)p, *(const floatx4*)(p + 4));
    }
    floatx4 acc[8];
#pragma unroll
    for (int f = 0; f < 8; ++f) acc[f] = (floatx4){0.f, 0.f, 0.f, 0.f};
    float m_run = -1e30f, l_run = 0.f;

    half8 AaL[4], AaH[4], AbL[4], AbH[4], Ba[8], Bb[8];

    auto LA = [&](half8 (&L_)[4], half8 (&H_)[4], const int t) {
#pragma unroll
      for (int c = 0; c < 4; ++c) {
        const int col = w * 128 + c * 32 + koff;
        L_[c] = loadAg<MODE>(Vhb, Vb, t * 32 + l15, col);
        H_[c] = loadAg<MODE>(Vhb, Vb, t * 32 + 16 + l15, col);
      }
    };
    auto LB = [&](half8 (&B_)[8], const int t) {
#pragma unroll
      for (int f = 0; f < 8; ++f)
        B_[f] = loadBg<MODE>(VhTb, Vb, w * 128 + f * 16 + l15, t * 32 + koff);
    };
    auto QK = [&](const half8 (&L_)[4], const half8 (&H_)[4], const int t) {
      floatx4 s0 = {0.f, 0.f, 0.f, 0.f}, s1 = s0;
#pragma unroll
      for (int c = 0; c < 4; ++c) {
        s0 = MFMA16(L_[c], qfrag[c], s0);    // S^T partial over wave's d-slice
        s1 = MFMA16(H_[c], qfrag[c], s1);
      }
      const unsigned swzq = (unsigned)((l15 & 7) << 4);
      const unsigned base = (unsigned)(t & 1) * 16384u + (unsigned)w * 2048u +
                            (unsigned)l15 * 128u;
      *(floatx4*)(REDb + base + (((unsigned)(hi * 16)) ^ swzq)) = s0;       // kv 4hi..
      *(floatx4*)(REDb + base + (((unsigned)(64 + hi * 16)) ^ swzq)) = s1;  // kv 16+4hi..
    };
    auto SM = [&](const int k) {
      const unsigned par = (unsigned)(k & 1);
      const unsigned roff = par * 16384u + (unsigned)row_sm * 128u +
                            (((unsigned)(kv_sm * 4)) ^ ((unsigned)((row_sm & 7) << 4)));
      float sv = 0.f;
#pragma unroll
      for (int ww = 0; ww < 8; ++ww)
        sv += *(const float*)(REDb + (unsigned)ww * 2048u + roff);   // D-reduction
      if (k * 32 + kv_sm > qbase + row_sm) sv = -1e30f;              // causal mask
      float pm = sv;
#pragma unroll
      for (int off = 1; off < 32; off <<= 1) pm = fmaxf(pm, __shfl_xor(pm, off));
      const float mnew = fmaxf(m_run, pm);
      const float al = __expf(m_run - mnew);
      const float p  = __expf(sv - mnew);
      float rs = p;
#pragma unroll
      for (int off = 1; off < 32; off <<= 1) rs += __shfl_xor(rs, off);
      l_run = l_run * al + rs;
      m_run = mnew;
      *(_Float16*)(PLb + par * 1024u + (unsigned)row_sm * 64u +
                   (((unsigned)(kv_sm * 2)) ^ ((unsigned)((row_sm & 3) << 4)))) = (_Float16)p;
      if (kv_sm == 0) AL[par][row_sm] = al;
    };
    auto PV = [&](const half8 (&B_)[8], const int t) {
      const unsigned par = (unsigned)(t & 1);
      float ar[4];
#pragma unroll
      for (int r = 0; r < 4; ++r) ar[r] = AL[par][4 * hi + r];
      const half8 pa = *(const half8*)(PLb + par * 1024u + (unsigned)l15 * 64u +
                        (((unsigned)(hi * 16)) ^ ((unsigned)((l15 & 3) << 4))));
#pragma unroll
      for (int f = 0; f < 8; ++f) {
#pragma unroll
        for (int r = 0; r < 4; ++r) acc[f][r] *= ar[r];
        acc[f] = MFMA16(pa, B_[f], acc[f]);
      }
    };

    // prologue: A(0),B(0),A(1); QK(0)->RED[0]
    LA(AaL, AaH, 0); LB(Ba, 0);
    if (n > 1) LA(AbL, AbH, 1);
    QK(AaL, AaH, 0);
    __syncthreads();

    int k = 0;
    for (;;) {
      // even step: PV(k-1) reads Bb; refill Bb with B(k+1); QK(k+1) uses Ab
      if (k > 0) PV(Bb, k - 1);
      if (k + 1 < n) { LB(Bb, k + 1); QK(AbL, AbH, k + 1); }
      if (k + 2 < n) LA(AaL, AaH, k + 2);
      SM(k);
      __syncthreads();
      if (++k == n) break;
      // odd step: mirrored buffers
      PV(Ba, k - 1);
      if (k + 1 < n) { LB(Ba, k + 1); QK(AaL, AaH, k + 1); }
      if (k + 2 < n) LA(AbL, AbH, k + 2);
      SM(k);
      __syncthreads();
      if (++k == n) break;
    }

    // epilogue: last PV (P/AL written by SM(n-1), separated by the final bar)
    if ((n - 1) & 1) PV(Bb, n - 1); else PV(Ba, n - 1);

    if (kv_sm == 0) Lsh[row_sm] = l_run;
    __syncthreads();
    float inv[4];
#pragma unroll
    for (int r = 0; r < 4; ++r) inv[r] = 1.0f / Lsh[4 * hi + r];
    float* Ob = Og + ((size_t)batch * T_ + qbase) * D_;
#pragma unroll
    for (int f = 0; f < 8; ++f) {
      const int dim = w * 128 + f * 16 + l15;
#pragma unroll
      for (int r = 0; r < 4; ++r)
        Ob[(size_t)(4 * hi + r) * D_ + dim] = acc[f][r] * inv[r];
    }
    __syncthreads();  // protect Lsh/RED/PL/AL before next strip
  }
}

extern "C" void kernel_launch(void* const* d_in, const int* in_sizes, int n_in,
                              void* d_out, int out_size, void* d_ws, size_t ws_size,
                              hipStream_t stream) {
  const float* q = (const float*)d_in[0];
  const float* v = (const float*)d_in[1];
  float* out = (float*)d_out;
  const size_t NE = (size_t)NB * T_ * D_;
  const size_t HB = NE * sizeof(_Float16);   // 16 MiB

  if (ws_size >= 2 * HB) {
    _Float16* vt = (_Float16*)d_ws;
    _Float16* vh = (_Float16*)((char*)d_ws + HB);
    prep<2><<<dim3(2048), dim3(256), 0, stream>>>(v, vt, vh);
    attn<2><<<dim3(256), dim3(512), 0, stream>>>(q, v, vt, vh, out);
  } else if (ws_size >= HB) {
    _Float16* vt = (_Float16*)d_ws;
    prep<1><<<dim3(2048), dim3(256), 0, stream>>>(v, vt, nullptr);
    attn<1><<<dim3(256), dim3(512), 0, stream>>>(q, v, vt, nullptr, out);
  } else {
    attn<0><<<dim3(256), dim3(512), 0, stream>>>(q, v, nullptr, nullptr, out);
  }
}

// Round 6
// 419.799 us; speedup vs baseline: 1.3272x; 1.3272x over previous
//
#include <hip/hip_runtime.h>
#include <hip/hip_fp16.h>

typedef _Float16 half8 __attribute__((ext_vector_type(8)));
typedef float    floatx4 __attribute__((ext_vector_type(4)));

#define MFMA16(a, b, c) __builtin_amdgcn_mfma_f32_16x16x32_f16((a), (b), (c), 0, 0, 0)

constexpr int T_ = 2048;
constexpr int D_ = 1024;
constexpr int NB = 4;

__device__ __forceinline__ half8 cvt8(floatx4 a, floatx4 b) {
  half8 h;
  h[0] = (_Float16)a[0]; h[1] = (_Float16)a[1]; h[2] = (_Float16)a[2]; h[3] = (_Float16)a[3];
  h[4] = (_Float16)b[0]; h[5] = (_Float16)b[1]; h[6] = (_Float16)b[2]; h[7] = (_Float16)b[3];
  return h;
}

// ---- prep: cast V->f16 (Vh) and build transposed VhT[D][T] ----
template <int MODE>
__global__ __launch_bounds__(256) void prep(const float* __restrict__ V,
                                            _Float16* __restrict__ VhT,
                                            _Float16* __restrict__ Vh) {
  __shared__ _Float16 tile[64][65];
  const int bid = blockIdx.x;
  const int b = bid & 3;
  const int tt = (bid >> 2) & 31;
  const int dd = bid >> 7;
  const float* Vb = V + ((size_t)b * T_ + tt * 64) * D_ + dd * 64;
#pragma unroll
  for (int k = 0; k < 16; ++k) {
    const int e = k * 256 + threadIdx.x;
    const int r = e >> 6, c = e & 63;
    const _Float16 h = (_Float16)Vb[(size_t)r * D_ + c];
    tile[r][c] = h;
    if (MODE == 2) Vh[((size_t)b * T_ + tt * 64 + r) * D_ + dd * 64 + c] = h;
  }
  __syncthreads();
#pragma unroll
  for (int k = 0; k < 16; ++k) {
    const int e = k * 256 + threadIdx.x;
    const int dr = e >> 6, tc = e & 63;
    VhT[((size_t)b * D_ + dd * 64 + dr) * T_ + tt * 64 + tc] = tile[tc][dr];
  }
}

template <int MODE>
__device__ __forceinline__ half8 loadAg(const _Float16* __restrict__ Vhb,
                                        const float* __restrict__ Vb, int row, int col) {
  if (MODE == 2) return *(const half8*)(Vhb + (size_t)row * D_ + col);
  const float* p = Vb + (size_t)row * D_ + col;
  return cvt8(*(const floatx4*)p, *(const floatx4*)(p + 4));
}

template <int MODE>
__device__ __forceinline__ half8 loadBg(const _Float16* __restrict__ VhTb,
                                        const float* __restrict__ Vb, int dim, int kv) {
  if (MODE >= 1) return *(const half8*)(VhTb + (size_t)dim * T_ + kv);
  half8 h;
#pragma unroll
  for (int j = 0; j < 8; ++j) h[j] = (_Float16)Vb[(size_t)(kv + j) * D_ + dim];
  return h;
}

// ---- causal flash attention, K=V, Br=16, Bc=32, kv-chunk split-K ----
// Q in LDS (frees VGPRs); single-buffered A/B reg frags with issue points
// placed >=1 barrier-interval before use; raw s_barrier (no vmcnt drain).
template <int MODE, bool SPLIT>
__global__ __launch_bounds__(512, 4) void attn(const float* __restrict__ Qg,
                                               const float* __restrict__ Vg,
                                               const _Float16* __restrict__ VhTg,
                                               const _Float16* __restrict__ Vhg,
                                               float* __restrict__ mlw,
                                               float* __restrict__ part,
                                               float* __restrict__ Og) {
  __shared__ __align__(16) char QL[16 * 2048];  // Q f16 [16 q][128 chunk16], XOR-swz
  __shared__ float RED[8][16][36];              // conflict-free (r2-verified)
  __shared__ _Float16 Psh[16][32];
  __shared__ float AL[16], LL[16];

  const int tid = threadIdx.x;
  const int w = tid >> 6, l = tid & 63, l15 = l & 15, hi = l >> 4;
  const int koff = hi * 8;
  const int row_sm = 2 * w + (l >> 5);
  const int kv_sm = l & 31;

  // ---- work item decode (LPT: big chunks dispatched first) ----
  int batch, s, t0, t1, chunk;
  if (SPLIT) {
    batch = (int)(blockIdx.x & 3);
    const int u = (int)(blockIdx.x >> 2);        // 0..253
    if (u < 252) {
      s = 127 - (u >> 1);
      const int n = (s + 2) >> 1, h = n >> 1;
      if (u & 1) { t0 = 0; t1 = h; chunk = 0; }
      else       { t0 = h; t1 = n; chunk = 1; }
    } else { s = 253 - u; t0 = 0; t1 = 1; chunk = 0; }   // strips 1,0 (single)
  } else {
    batch = (int)(blockIdx.x & 3);
    s = 127 - (int)(blockIdx.x >> 2);
    t0 = 0; t1 = (s + 2) >> 1; chunk = 0;
  }
  const int qbase = s * 16;
  const bool full = (t0 == 0) && (t1 == ((s + 2) >> 1));

  const float* Qb = Qg + (size_t)batch * T_ * D_;
  const float* Vb = Vg + (size_t)batch * T_ * D_;
  const _Float16* VhTb = (MODE >= 1) ? VhTg + (size_t)batch * T_ * D_ : (const _Float16*)nullptr;
  const _Float16* Vhb  = (MODE == 2) ? Vhg  + (size_t)batch * T_ * D_ : (const _Float16*)nullptr;

  // ---- stage Q strip (f32 -> f16) into XOR-swizzled LDS ----
  {
    const int row = tid >> 5, c32 = tid & 31;
    const float* qr = Qb + (size_t)(qbase + row) * D_;
#pragma unroll
    for (int i = 0; i < 4; ++i) {
      const int ch = c32 + i * 32;               // 16B-chunk index 0..127
      const float* p = qr + ch * 8;
      half8 h = cvt8(*(const floatx4*)p, *(const floatx4*)(p + 4));
      *(half8*)(QL + row * 2048 + ((ch ^ (row & 7)) << 4)) = h;
    }
  }
  __syncthreads();  // once per block; prologue loads issued after (no drain loss)

  floatx4 acc[8];
#pragma unroll
  for (int f = 0; f < 8; ++f) acc[f] = (floatx4){0.f, 0.f, 0.f, 0.f};
  float m_run = -1e30f, l_run = 0.f;

  half8 A0[4], A1[4], Bv[8];
  auto LA = [&](const int t) {
#pragma unroll
    for (int c = 0; c < 4; ++c) {
      const int col = w * 128 + c * 32 + koff;
      A0[c] = loadAg<MODE>(Vhb, Vb, t * 32 + l15, col);
      A1[c] = loadAg<MODE>(Vhb, Vb, t * 32 + 16 + l15, col);
    }
  };
  auto LB = [&](const int t) {
#pragma unroll
    for (int f = 0; f < 8; ++f)
      Bv[f] = loadBg<MODE>(VhTb, Vb, w * 128 + f * 16 + l15, t * 32 + koff);
  };

  LA(t0); LB(t0);

  for (int t = t0; t < t1; ++t) {
    // ---- QK: S^T partial over wave's 128-d slice; Q frags from LDS ----
    floatx4 s0 = {0.f, 0.f, 0.f, 0.f}, s1 = s0;
#pragma unroll
    for (int c = 0; c < 4; ++c) {
      const half8 qf = *(const half8*)(QL + l15 * 2048 +
                        (((w * 16 + c * 4 + hi) ^ (l15 & 7)) << 4));
      s0 = MFMA16(A0[c], qf, s0);
      s1 = MFMA16(A1[c], qf, s1);
    }
    if (t + 1 < t1) LA(t + 1);   // A regs free; in flight across raw barriers
    *(floatx4*)&RED[w][l15][4 * hi]      = s0;
    *(floatx4*)&RED[w][l15][16 + 4 * hi] = s1;
    asm volatile("s_waitcnt lgkmcnt(0)" ::: "memory");
    __builtin_amdgcn_s_barrier();              // bar A (no vmcnt drain)
    __builtin_amdgcn_sched_barrier(0);

    {  // ---- wave-parallel online softmax: thread owns (row_sm, kv_sm) ----
      float sv = 0.f;
#pragma unroll
      for (int ww = 0; ww < 8; ++ww) sv += RED[ww][row_sm][kv_sm];
      if (t * 32 + kv_sm > qbase + row_sm) sv = -1e30f;    // causal mask
      float pm = sv;
#pragma unroll
      for (int off = 1; off < 32; off <<= 1) pm = fmaxf(pm, __shfl_xor(pm, off));
      const float mnew = fmaxf(m_run, pm);
      const float al = __expf(m_run - mnew);
      const float p  = __expf(sv - mnew);
      float rs = p;
#pragma unroll
      for (int off = 1; off < 32; off <<= 1) rs += __shfl_xor(rs, off);
      l_run = l_run * al + rs;
      m_run = mnew;
      Psh[row_sm][kv_sm] = (_Float16)p;
      if (kv_sm == 0) AL[row_sm] = al;
    }
    asm volatile("s_waitcnt lgkmcnt(0)" ::: "memory");
    __builtin_amdgcn_s_barrier();              // bar B
    __builtin_amdgcn_sched_barrier(0);

    // ---- PV: O[16 q][128-d slice] += P[16][32] * V^T ----
    const half8 pa = *(const half8*)&Psh[l15][koff];
    float ar[4];
#pragma unroll
    for (int r = 0; r < 4; ++r) ar[r] = AL[4 * hi + r];
#pragma unroll
    for (int f = 0; f < 8; ++f) {
#pragma unroll
      for (int r = 0; r < 4; ++r) acc[f][r] *= ar[r];
      acc[f] = MFMA16(pa, Bv[f], acc[f]);
    }
    if (t + 1 < t1) LB(t + 1);   // B regs free; consumed at PV(t+1)
  }

  if (full) {
    if (kv_sm == 0) LL[row_sm] = l_run;
    asm volatile("s_waitcnt lgkmcnt(0)" ::: "memory");
    __builtin_amdgcn_s_barrier();
    __builtin_amdgcn_sched_barrier(0);
    float inv[4];
#pragma unroll
    for (int r = 0; r < 4; ++r) inv[r] = 1.0f / LL[4 * hi + r];
    float* Ob = Og + ((size_t)batch * T_ + qbase) * D_;
#pragma unroll
    for (int f = 0; f < 8; ++f) {
      const int dim = w * 128 + f * 16 + l15;
#pragma unroll
      for (int r = 0; r < 4; ++r)
        Ob[(size_t)(4 * hi + r) * D_ + dim] = acc[f][r] * inv[r];
    }
  } else {
    // raw partial: chunk0 -> output region (combined later), chunk1 -> ws
    float* dst = (chunk == 0) ? Og + ((size_t)batch * T_ + qbase) * D_
                              : part + (size_t)(batch * 128 + s) * 16384;
#pragma unroll
    for (int f = 0; f < 8; ++f) {
      const int dim = w * 128 + f * 16 + l15;
#pragma unroll
      for (int r = 0; r < 4; ++r)
        dst[(size_t)(4 * hi + r) * 1024 + dim] = acc[f][r];
    }
    if (kv_sm == 0) {
      float* mp = mlw + (size_t)(batch * 128 + s) * 64 + chunk * 32;
      mp[row_sm] = m_run;
      mp[16 + row_sm] = l_run;
    }
  }
}

// ---- combine two kv-chunk partials per strip (s >= 2) ----
__global__ __launch_bounds__(256) void combine(const float* __restrict__ mlw,
                                               const float* __restrict__ part,
                                               float* __restrict__ Og) {
  const int batch = (int)(blockIdx.x & 3);
  const int s = 2 + (int)(blockIdx.x >> 2);
  const int pid = batch * 128 + s;
  const int row = threadIdx.x >> 4;            // 0..15
  const int seg = threadIdx.x & 15;            // 64 cols each
  const float* mp = mlw + (size_t)pid * 64;
  const float m0 = mp[row], l0 = mp[16 + row];
  const float m1 = mp[32 + row], l1 = mp[48 + row];
  const float M = fmaxf(m0, m1);
  const float w0 = __expf(m0 - M), w1 = __expf(m1 - M);
  const float inv = 1.0f / (w0 * l0 + w1 * l1);
  floatx4* o = (floatx4*)(Og + ((size_t)batch * T_ + s * 16 + row) * D_ + seg * 64);
  const floatx4* p1 = (const floatx4*)(part + (size_t)pid * 16384 + row * 1024 + seg * 64);
#pragma unroll
  for (int j = 0; j < 16; ++j) {
    floatx4 a = o[j], b = p1[j];
#pragma unroll
    for (int r = 0; r < 4; ++r) a[r] = (w0 * a[r] + w1 * b[r]) * inv;
    o[j] = a;
  }
}

extern "C" void kernel_launch(void* const* d_in, const int* in_sizes, int n_in,
                              void* d_out, int out_size, void* d_ws, size_t ws_size,
                              hipStream_t stream) {
  const float* q = (const float*)d_in[0];
  const float* v = (const float*)d_in[1];
  float* out = (float*)d_out;
  const size_t NE = (size_t)NB * T_ * D_;
  const size_t HB = NE * sizeof(_Float16);             // 16 MiB
  const size_t PARTB = (size_t)512 * 16384 * 4;        // 32 MiB partials
  const size_t MLB = (size_t)512 * 64 * 4;             // 128 KiB m/l
  const size_t NEED_SPLIT = 2 * HB + PARTB + MLB;      // ~67.2 MB

  if (ws_size >= NEED_SPLIT) {
    _Float16* vt = (_Float16*)d_ws;
    _Float16* vh = (_Float16*)((char*)d_ws + HB);
    float* part = (float*)((char*)d_ws + 2 * HB);
    float* mlw  = (float*)((char*)d_ws + 2 * HB + PARTB);
    prep<2><<<dim3(2048), dim3(256), 0, stream>>>(v, vt, vh);
    attn<2, true><<<dim3(1016), dim3(512), 0, stream>>>(q, v, vt, vh, mlw, part, out);
    combine<<<dim3(504), dim3(256), 0, stream>>>(mlw, part, out);
  } else if (ws_size >= 2 * HB) {
    _Float16* vt = (_Float16*)d_ws;
    _Float16* vh = (_Float16*)((char*)d_ws + HB);
    prep<2><<<dim3(2048), dim3(256), 0, stream>>>(v, vt, vh);
    attn<2, false><<<dim3(512), dim3(512), 0, stream>>>(q, v, vt, vh, nullptr, nullptr, out);
  } else if (ws_size >= HB) {
    _Float16* vt = (_Float16*)d_ws;
    prep<1><<<dim3(2048), dim3(256), 0, stream>>>(v, vt, nullptr);
    attn<1, false><<<dim3(512), dim3(512), 0, stream>>>(q, v, vt, nullptr, nullptr, nullptr, out);
  } else {
    attn<0, false><<<dim3(512), dim3(512), 0, stream>>>(q, v, nullptr, nullptr, nullptr, nullptr, out);
  }
}

// Round 7
// 145.948 us; speedup vs baseline: 3.8174x; 2.8764x over previous
//
#include <hip/hip_runtime.h>
#include <hip/hip_fp16.h>

typedef _Float16 half8 __attribute__((ext_vector_type(8)));
typedef _Float16 half2v __attribute__((ext_vector_type(2)));
typedef float    floatx4 __attribute__((ext_vector_type(4)));

#define MFMA16(a, b, c) __builtin_amdgcn_mfma_f32_16x16x32_f16((a), (b), (c), 0, 0, 0)

constexpr int T_ = 2048;
constexpr int D_ = 1024;
constexpr int NB = 4;
constexpr int NTILE = 136;             // lower-tri 128x128 tiles per batch
constexpr size_t TILE_ELEMS = 16384;   // 128*128

__device__ __forceinline__ half8 cvt8(floatx4 a, floatx4 b) {
  half8 h;
  h[0] = (_Float16)a[0]; h[1] = (_Float16)a[1]; h[2] = (_Float16)a[2]; h[3] = (_Float16)a[3];
  h[4] = (_Float16)b[0]; h[5] = (_Float16)b[1]; h[6] = (_Float16)b[2]; h[7] = (_Float16)b[3];
  return h;
}

// ---- prep 1: Q f32 -> f16 straight cast ----
__global__ __launch_bounds__(256) void cast_q(const float* __restrict__ Q,
                                              _Float16* __restrict__ Qh) {
  const size_t i = ((size_t)blockIdx.x * 256 + threadIdx.x) * 8;
  *(half8*)(Qh + i) = cvt8(*(const floatx4*)(Q + i), *(const floatx4*)(Q + i + 4));
}

// ---- prep 2: build VhT[b][d][t] f16 (for PV B-operand) ----
__global__ __launch_bounds__(256) void build_vt(const float* __restrict__ V,
                                                _Float16* __restrict__ VhT) {
  __shared__ _Float16 tile[64][65];
  const int bid = blockIdx.x;
  const int b = bid & 3, tt = (bid >> 2) & 31, dd = bid >> 7;
  const float* Vb = V + ((size_t)b * T_ + tt * 64) * D_ + dd * 64;
#pragma unroll
  for (int k = 0; k < 16; ++k) {
    const int e = k * 256 + threadIdx.x, r = e >> 6, c = e & 63;
    tile[r][c] = (_Float16)Vb[(size_t)r * D_ + c];
  }
  __syncthreads();
#pragma unroll
  for (int k = 0; k < 16; ++k) {
    const int e = k * 256 + threadIdx.x, dr = e >> 6, tc = e & 63;
    VhT[((size_t)b * D_ + dd * 64 + dr) * T_ + tt * 64 + tc] = tile[tc][dr];
  }
}

// ---- S-GEMM: packed lower-tri tiles, S = Q*V^T (NT), 128^2 tile, BK=64 ----
__global__ __launch_bounds__(256, 2) void sgemm(const _Float16* __restrict__ Qh,
                                                const float* __restrict__ V,
                                                float* __restrict__ Sp) {
  extern __shared__ char lds[];                 // [2][128][64] f16 A, then B (64 KB)
  const int tid = threadIdx.x;
  const int w = tid >> 6, l = tid & 63, l15 = l & 15, hi = l >> 4;
  const int wr = (w >> 1) * 64, wc = (w & 1) * 64;

  const int b = (int)(blockIdx.x & 3);
  int rem = (int)(blockIdx.x >> 2), j = 0;      // j-major decode (B-panel L2 reuse)
  while (rem >= 16 - j) { rem -= 16 - j; ++j; }
  const int i = j + rem;

  const _Float16* Arow = Qh + ((size_t)b * T_ + i * 128 + (tid >> 1)) * D_ + (tid & 1) * 32;
  const float*    Brow = V  + ((size_t)b * T_ + j * 128 + (tid >> 1)) * D_ + (tid & 1) * 32;
  const int srow = tid >> 1, sseg = tid & 1;

  floatx4 acc[4][4];
#pragma unroll
  for (int mi = 0; mi < 4; ++mi)
#pragma unroll
    for (int ni = 0; ni < 4; ++ni) acc[mi][ni] = (floatx4){0.f, 0.f, 0.f, 0.f};

  half8 al[4]; floatx4 bf[8];
  auto LOADS = [&](const int s) {
#pragma unroll
    for (int q = 0; q < 4; ++q) al[q] = *(const half8*)(Arow + s * 64 + q * 8);
#pragma unroll
    for (int q = 0; q < 8; ++q) bf[q] = *(const floatx4*)(Brow + s * 64 + q * 4);
  };
  auto WRITES = [&](const int buf) {
    char* A = lds + buf * 16384;
    char* B = lds + 32768 + buf * 16384;
#pragma unroll
    for (int q = 0; q < 4; ++q) {
      const int sw = srow * 128 + ((((sseg << 2) | q) ^ (srow & 7)) << 4);
      *(half8*)(A + sw) = al[q];
      *(half8*)(B + sw) = cvt8(bf[2 * q], bf[2 * q + 1]);
    }
  };
  auto COMP = [&](const int buf) {
    const char* A = lds + buf * 16384;
    const char* B = lds + 32768 + buf * 16384;
#pragma unroll
    for (int s32 = 0; s32 < 2; ++s32) {
      half8 af[4], bb[4];
#pragma unroll
      for (int mi = 0; mi < 4; ++mi) {
        const int row = wr + mi * 16 + l15;
        af[mi] = *(const half8*)(A + row * 128 + ((((s32 << 2) | hi) ^ (row & 7)) << 4));
      }
#pragma unroll
      for (int ni = 0; ni < 4; ++ni) {
        const int row = wc + ni * 16 + l15;
        bb[ni] = *(const half8*)(B + row * 128 + ((((s32 << 2) | hi) ^ (row & 7)) << 4));
      }
#pragma unroll
      for (int mi = 0; mi < 4; ++mi)
#pragma unroll
        for (int ni = 0; ni < 4; ++ni) acc[mi][ni] = MFMA16(af[mi], bb[ni], acc[mi][ni]);
    }
  };

  LOADS(0); WRITES(0); __syncthreads();
  for (int s = 0; s < 16; ++s) {
    if (s + 1 < 16) LOADS(s + 1);     // in flight across the MFMA block
    COMP(s & 1);
    if (s + 1 < 16) WRITES((s + 1) & 1);
    __syncthreads();
  }

  float* tp = Sp + (size_t)(b * NTILE + ((i * (i + 1)) >> 1) + j) * TILE_ELEMS;
#pragma unroll
  for (int mi = 0; mi < 4; ++mi)
#pragma unroll
    for (int r = 0; r < 4; ++r) {
      const int row = wr + mi * 16 + 4 * hi + r;
#pragma unroll
      for (int ni = 0; ni < 4; ++ni)
        tp[row * 128 + wc + ni * 16 + l15] = acc[mi][ni][r];
    }
}

// ---- softmax: one wave per row; P=exp(s-m) f16 in-place (first half of row) ----
__global__ __launch_bounds__(256) void smax(float* __restrict__ Sp,
                                            float* __restrict__ lrow) {
  const int b = (int)(blockIdx.x & 3), t = (int)(blockIdx.x >> 2);
  const int i = 15 - (t >> 5), rg = t & 31;
  const int w = threadIdx.x >> 6, l = threadIdx.x & 63;
  const int r = rg * 4 + w, m = i * 128 + r, len = m + 1;
  char* tb0 = (char*)(Sp + (size_t)(b * NTILE + ((i * (i + 1)) >> 1)) * TILE_ELEMS);

  float mx = -1e30f;
  for (int j = 0; j <= i; ++j) {
    const float* tp = (const float*)(tb0 + (size_t)j * 65536) + r * 128 + l * 2;
    const float v0 = tp[0], v1 = tp[1];
    const int col = j * 128 + l * 2;
    if (col < len) mx = fmaxf(mx, v0);
    if (col + 1 < len) mx = fmaxf(mx, v1);
  }
#pragma unroll
  for (int off = 1; off < 64; off <<= 1) mx = fmaxf(mx, __shfl_xor(mx, off));

  float sum = 0.f;
  for (int j = 0; j <= i; ++j) {
    char* tbj = tb0 + (size_t)j * 65536;
    const float* tp = (const float*)tbj + r * 128 + l * 2;
    const float v0 = tp[0], v1 = tp[1];            // read (all lanes, lockstep)
    const int col = j * 128 + l * 2;
    const float p0 = (col < len) ? __expf(v0 - mx) : 0.f;
    const float p1 = (col + 1 < len) ? __expf(v1 - mx) : 0.f;
    sum += p0 + p1;
    half2v hv; hv[0] = (_Float16)p0; hv[1] = (_Float16)p1;
    *(half2v*)(tbj + r * 512 + l * 4) = hv;        // then write (same row only)
  }
#pragma unroll
  for (int off = 1; off < 64; off <<= 1) sum += __shfl_xor(sum, off);
  if (l == 0) lrow[b * 2048 + m] = sum;
}

// ---- PV: O = P*V (NN via VhT), 128^2 tile, K extent (i+1)*128, LPT order ----
__global__ __launch_bounds__(256, 2) void pv(const float* __restrict__ Sp,
                                             const _Float16* __restrict__ VhT,
                                             const float* __restrict__ lrow,
                                             float* __restrict__ O) {
  extern __shared__ char lds[];                  // A 32KB | B 32KB | Lsh 512B
  float* Lsh = (float*)(lds + 65536);
  const int tid = threadIdx.x;
  const int w = tid >> 6, l = tid & 63, l15 = l & 15, hi = l >> 4;
  const int wr = (w >> 1) * 64, wc = (w & 1) * 64;

  const int b = (int)(blockIdx.x & 3), t = (int)(blockIdx.x >> 2);
  const int i = 15 - (t >> 3), nc = t & 7;       // big-i blocks dispatch first
  const int ns = (i + 1) * 2;

  const char* Pbase = (const char*)(Sp + (size_t)(b * NTILE + ((i * (i + 1)) >> 1)) * TILE_ELEMS);
  const _Float16* Bp = VhT + ((size_t)b * D_ + nc * 128 + (tid >> 1)) * T_ + (tid & 1) * 32;
  const int srow = tid >> 1, sseg = tid & 1;
  if (tid < 128) Lsh[tid] = lrow[b * 2048 + i * 128 + tid];

  floatx4 acc[4][4];
#pragma unroll
  for (int mi = 0; mi < 4; ++mi)
#pragma unroll
    for (int ni = 0; ni < 4; ++ni) acc[mi][ni] = (floatx4){0.f, 0.f, 0.f, 0.f};

  half8 al[4], bl[4];
  auto LOADS = [&](const int s) {
    const char* ap = Pbase + (size_t)(s >> 1) * 65536 + srow * 512 + (s & 1) * 128 + sseg * 64;
#pragma unroll
    for (int q = 0; q < 4; ++q) al[q] = *(const half8*)(ap + q * 16);
#pragma unroll
    for (int q = 0; q < 4; ++q) bl[q] = *(const half8*)(Bp + s * 64 + q * 8);
  };
  auto WRITES = [&](const int buf) {
    char* A = lds + buf * 16384;
    char* B = lds + 32768 + buf * 16384;
#pragma unroll
    for (int q = 0; q < 4; ++q) {
      const int sw = srow * 128 + ((((sseg << 2) | q) ^ (srow & 7)) << 4);
      *(half8*)(A + sw) = al[q];
      *(half8*)(B + sw) = bl[q];
    }
  };
  auto COMP = [&](const int buf) {
    const char* A = lds + buf * 16384;
    const char* B = lds + 32768 + buf * 16384;
#pragma unroll
    for (int s32 = 0; s32 < 2; ++s32) {
      half8 af[4], bb[4];
#pragma unroll
      for (int mi = 0; mi < 4; ++mi) {
        const int row = wr + mi * 16 + l15;
        af[mi] = *(const half8*)(A + row * 128 + ((((s32 << 2) | hi) ^ (row & 7)) << 4));
      }
#pragma unroll
      for (int ni = 0; ni < 4; ++ni) {
        const int row = wc + ni * 16 + l15;
        bb[ni] = *(const half8*)(B + row * 128 + ((((s32 << 2) | hi) ^ (row & 7)) << 4));
      }
#pragma unroll
      for (int mi = 0; mi < 4; ++mi)
#pragma unroll
        for (int ni = 0; ni < 4; ++ni) acc[mi][ni] = MFMA16(af[mi], bb[ni], acc[mi][ni]);
    }
  };

  LOADS(0); WRITES(0); __syncthreads();
  for (int s = 0; s < ns; ++s) {
    if (s + 1 < ns) LOADS(s + 1);
    COMP(s & 1);
    if (s + 1 < ns) WRITES((s + 1) & 1);
    __syncthreads();
  }

  float* Ob = O + ((size_t)b * T_ + i * 128) * D_ + nc * 128;
#pragma unroll
  for (int mi = 0; mi < 4; ++mi)
#pragma unroll
    for (int r = 0; r < 4; ++r) {
      const int rl = wr + mi * 16 + 4 * hi + r;
      const float inv = 1.0f / Lsh[rl];
#pragma unroll
      for (int ni = 0; ni < 4; ++ni)
        Ob[(size_t)rl * D_ + wc + ni * 16 + l15] = acc[mi][ni][r] * inv;
    }
}

// ---- fallback (ws too small — not expected to run; slow but correct) ----
__global__ __launch_bounds__(256) void attn_fb(const float* __restrict__ Q,
                                               const float* __restrict__ V,
                                               float* __restrict__ O) {
  __shared__ float sc[2048];
  __shared__ float red[4];
  const int b = (int)(blockIdx.x >> 11), m = (int)(blockIdx.x & 2047);
  const int tid = threadIdx.x;
  const float* Qr = Q + ((size_t)b * T_ + m) * D_;
  for (int kv = tid; kv <= m; kv += 256) {
    const float* Vr = V + ((size_t)b * T_ + kv) * D_;
    float s = 0.f;
    for (int d = 0; d < D_; d += 4) {
      floatx4 q4 = *(const floatx4*)(Qr + d), v4 = *(const floatx4*)(Vr + d);
      s += q4[0] * v4[0] + q4[1] * v4[1] + q4[2] * v4[2] + q4[3] * v4[3];
    }
    sc[kv] = s;
  }
  __syncthreads();
  float mx = -1e30f;
  for (int kv = tid; kv <= m; kv += 256) mx = fmaxf(mx, sc[kv]);
#pragma unroll
  for (int off = 1; off < 64; off <<= 1) mx = fmaxf(mx, __shfl_xor(mx, off));
  if ((tid & 63) == 0) red[tid >> 6] = mx;
  __syncthreads();
  mx = fmaxf(fmaxf(red[0], red[1]), fmaxf(red[2], red[3]));
  __syncthreads();
  float sum = 0.f;
  for (int kv = tid; kv <= m; kv += 256) { float p = __expf(sc[kv] - mx); sc[kv] = p; sum += p; }
#pragma unroll
  for (int off = 1; off < 64; off <<= 1) sum += __shfl_xor(sum, off);
  __syncthreads();
  if ((tid & 63) == 0) red[tid >> 6] = sum;
  __syncthreads();
  const float inv = 1.0f / (red[0] + red[1] + red[2] + red[3]);
  float* Or = O + ((size_t)b * T_ + m) * D_;
  const int d = tid * 4;
  floatx4 o = {0.f, 0.f, 0.f, 0.f};
  for (int kv = 0; kv <= m; ++kv) {
    const float p = sc[kv];
    const floatx4 v4 = *(const floatx4*)(V + ((size_t)b * T_ + kv) * D_ + d);
    o[0] += p * v4[0]; o[1] += p * v4[1]; o[2] += p * v4[2]; o[3] += p * v4[3];
  }
  o[0] *= inv; o[1] *= inv; o[2] *= inv; o[3] *= inv;
  *(floatx4*)(Or + d) = o;
}

extern "C" void kernel_launch(void* const* d_in, const int* in_sizes, int n_in,
                              void* d_out, int out_size, void* d_ws, size_t ws_size,
                              hipStream_t stream) {
  const float* q = (const float*)d_in[0];
  const float* v = (const float*)d_in[1];
  float* out = (float*)d_out;

  const size_t OFF_S = 16777216;                                   // Qh/VhT slot (reused)
  const size_t OFF_L = OFF_S + (size_t)NB * NTILE * TILE_ELEMS * 4; // 52,428,800
  const size_t NEED = OFF_L + (size_t)NB * 2048 * 4;                // ~52.5 MB (ws >= 67.2 proven)

  if (ws_size >= NEED) {
    _Float16* fh = (_Float16*)d_ws;                 // Qh, later VhT
    float* Sp = (float*)((char*)d_ws + OFF_S);
    float* lr = (float*)((char*)d_ws + OFF_L);
    hipFuncSetAttribute((const void*)sgemm, hipFuncAttributeMaxDynamicSharedMemorySize, 65536);
    hipFuncSetAttribute((const void*)pv, hipFuncAttributeMaxDynamicSharedMemorySize, 66048);
    cast_q<<<dim3(4096), dim3(256), 0, stream>>>(q, fh);
    sgemm<<<dim3(NB * NTILE), dim3(256), 65536, stream>>>(fh, v, Sp);
    smax<<<dim3(2048), dim3(256), 0, stream>>>(Sp, lr);
    build_vt<<<dim3(2048), dim3(256), 0, stream>>>(v, fh);   // Qh dead -> VhT
    pv<<<dim3(512), dim3(256), 66048, stream>>>(Sp, fh, lr, out);
  } else {
    attn_fb<<<dim3(NB * T_), dim3(256), 0, stream>>>(q, v, out);
  }
}

// Round 8
// 110.403 us; speedup vs baseline: 5.0465x; 1.3220x over previous
//
#include <hip/hip_runtime.h>
#include <hip/hip_fp16.h>

typedef _Float16 half8 __attribute__((ext_vector_type(8)));
typedef _Float16 half2v __attribute__((ext_vector_type(2)));
typedef float    floatx4 __attribute__((ext_vector_type(4)));

#define MFMA16(a, b, c) __builtin_amdgcn_mfma_f32_16x16x32_f16((a), (b), (c), 0, 0, 0)

constexpr int T_ = 2048;
constexpr int D_ = 1024;
constexpr int NB = 4;
constexpr int NTILE = 136;             // lower-tri 128x128 tiles per batch
constexpr size_t TILE_ELEMS = 16384;   // 128*128

__device__ __forceinline__ half8 cvt8(floatx4 a, floatx4 b) {
  half8 h;
  h[0] = (_Float16)a[0]; h[1] = (_Float16)a[1]; h[2] = (_Float16)a[2]; h[3] = (_Float16)a[3];
  h[4] = (_Float16)b[0]; h[5] = (_Float16)b[1]; h[6] = (_Float16)b[2]; h[7] = (_Float16)b[3];
  return h;
}

// async global->LDS, 16B per lane; LDS dest is wave-uniform base + lane*16
__device__ __forceinline__ void gl16(const void* g, void* l) {
  __builtin_amdgcn_global_load_lds(
      (const __attribute__((address_space(1))) void*)g,
      (__attribute__((address_space(3))) void*)l, 16, 0, 0);
}

// ---- prep 1: Q f32 -> f16, XOR-swizzle baked per 64-col window ----
__global__ __launch_bounds__(256) void cast_q(const float* __restrict__ Q,
                                              _Float16* __restrict__ Qh) {
  const size_t e = ((size_t)blockIdx.x * 256 + threadIdx.x) * 8;
  const int t = (int)(e >> 10);          // global row
  const int c = (int)((e >> 3) & 127);   // 8-elem chunk in row
  const int cd = (c & ~7) | ((c ^ t) & 7);
  half8 h = cvt8(*(const floatx4*)(Q + e), *(const floatx4*)(Q + e + 4));
  *(half8*)(Qh + ((size_t)t << 10) + (cd << 3)) = h;
}

// ---- prep 2: VhT[b][d][t] f16, XOR-swizzle baked per 64-col window ----
__global__ __launch_bounds__(256) void build_vt(const float* __restrict__ V,
                                                _Float16* __restrict__ VhT) {
  __shared__ _Float16 tile[64][65];
  const int bid = blockIdx.x;
  const int b = bid & 3, tt = (bid >> 2) & 31, dd = bid >> 7;
  const float* Vb = V + ((size_t)b * T_ + tt * 64) * D_ + dd * 64;
#pragma unroll
  for (int k = 0; k < 16; ++k) {
    const int e = k * 256 + threadIdx.x, r = e >> 6, c = e & 63;
    tile[r][c] = (_Float16)Vb[(size_t)r * D_ + c];
  }
  __syncthreads();
#pragma unroll
  for (int k = 0; k < 16; ++k) {
    const int e = k * 256 + threadIdx.x, dr = e >> 6, tc = e & 63;
    const int tcd = ((((tc >> 3) ^ dr) & 7) << 3) | (tc & 7);
    VhT[((size_t)b * D_ + dd * 64 + dr) * T_ + tt * 64 + tcd] = tile[tc][dr];
  }
}

// ---- S-GEMM: S = Q*V^T (NT), 128^2 tile, BK=64, global_load_lds staging ----
__global__ __launch_bounds__(256, 3) void sgemm(const _Float16* __restrict__ Qh,
                                                const float* __restrict__ V,
                                                float* __restrict__ Sp) {
  __shared__ __align__(16) char As[16384];   // [128 rows][64 k] f16, chunk-swizzled
  __shared__ __align__(16) char Bs[32768];   // [128 rows][64 k] f32, chunk-swizzled
  const int tid = threadIdx.x;
  const int w = tid >> 6, l = tid & 63, l15 = l & 15, hi = l >> 4;
  const int wr = (w >> 1) * 64, wc = (w & 1) * 64;

  const int b = (int)(blockIdx.x & 3);
  int rem = (int)(blockIdx.x >> 2), j = 0;      // j-major (B-panel L2 reuse)
  while (rem >= 16 - j) { rem -= 16 - j; ++j; }
  const int i = j + rem;

  // staging: A rows w*32+q*8+(l>>3), lane chunk l&7 (source pre-swizzled);
  //          B rows w*32+q*4+(l>>4), lane chunk l&15, source XOR'd per lane
  const int arow = w * 32 + (l >> 3);
  const int brow = w * 32 + (l >> 4);
  const _Float16* Asrc = Qh + ((size_t)(b * T_ + i * 128 + arow)) * D_ + (l & 7) * 8;
  const float* Bb = V + ((size_t)(b * T_ + j * 128 + brow)) * D_;
  const int lc0 = (l & 8) | ((l & 7) ^ (l >> 4));   // logical chunk, even q
  char* Adst = As + w * 4096;
  char* Bdst = Bs + w * 8192;

  floatx4 acc[4][4];
#pragma unroll
  for (int mi = 0; mi < 4; ++mi)
#pragma unroll
    for (int ni = 0; ni < 4; ++ni) acc[mi][ni] = (floatx4){0.f, 0.f, 0.f, 0.f};

  for (int s = 0; s < 16; ++s) {
#pragma unroll
    for (int q = 0; q < 4; ++q)
      gl16(Asrc + (size_t)q * 8 * D_ + s * 64, Adst + q * 1024);
#pragma unroll
    for (int q = 0; q < 8; ++q)
      gl16(Bb + (size_t)q * 4 * D_ + s * 64 + (lc0 ^ ((q & 1) << 2)) * 4,
           Bdst + q * 1024);
    __syncthreads();                        // vmcnt drain -> tiles ready
#pragma unroll
    for (int s32 = 0; s32 < 2; ++s32) {
      half8 af[4], bb[4];
#pragma unroll
      for (int mi = 0; mi < 4; ++mi) {
        const int row = wr + mi * 16 + l15;
        af[mi] = *(const half8*)(As + row * 128 + ((((s32 << 2) | hi) ^ (row & 7)) << 4));
      }
#pragma unroll
      for (int ni = 0; ni < 4; ++ni) {
        const int row = wc + ni * 16 + l15;
        const int p0 = (s32 << 3) | (((hi << 1) ^ row) & 7);
        const floatx4 f0 = *(const floatx4*)(Bs + row * 256 + (p0 << 4));
        const floatx4 f1 = *(const floatx4*)(Bs + row * 256 + ((p0 ^ 1) << 4));
        bb[ni] = cvt8(f0, f1);
      }
#pragma unroll
      for (int mi = 0; mi < 4; ++mi)
#pragma unroll
        for (int ni = 0; ni < 4; ++ni)
          acc[mi][ni] = MFMA16(af[mi], bb[ni], acc[mi][ni]);
    }
    __syncthreads();                        // done reading before next stage
  }

  float* tp = Sp + (size_t)(b * NTILE + ((i * (i + 1)) >> 1) + j) * TILE_ELEMS;
#pragma unroll
  for (int mi = 0; mi < 4; ++mi)
#pragma unroll
    for (int r = 0; r < 4; ++r) {
      const int row = wr + mi * 16 + 4 * hi + r;
#pragma unroll
      for (int ni = 0; ni < 4; ++ni)
        tp[row * 128 + wc + ni * 16 + l15] = acc[mi][ni][r];
    }
}

// ---- softmax: P=exp(s-m) f16 in-place, XOR-swizzle baked into write ----
__global__ __launch_bounds__(256) void smax(float* __restrict__ Sp,
                                            float* __restrict__ lrow) {
  const int b = (int)(blockIdx.x & 3), t = (int)(blockIdx.x >> 2);
  const int i = 15 - (t >> 5), rg = t & 31;
  const int w = threadIdx.x >> 6, l = threadIdx.x & 63;
  const int r = rg * 4 + w, m = i * 128 + r, len = m + 1;
  char* tb0 = (char*)(Sp + (size_t)(b * NTILE + ((i * (i + 1)) >> 1)) * TILE_ELEMS);

  float mx = -1e30f;
  for (int j = 0; j <= i; ++j) {
    const float* tp = (const float*)(tb0 + (size_t)j * 65536) + r * 128 + l * 2;
    const float v0 = tp[0], v1 = tp[1];
    const int col = j * 128 + l * 2;
    if (col < len) mx = fmaxf(mx, v0);
    if (col + 1 < len) mx = fmaxf(mx, v1);
  }
#pragma unroll
  for (int off = 1; off < 64; off <<= 1) mx = fmaxf(mx, __shfl_xor(mx, off));

  const int ch = (l >> 2) & 7, hf = l >> 5;            // swizzled P position
  const unsigned pb = (unsigned)(r * 512 + hf * 128 + ((ch ^ (r & 7)) << 4) + (l & 3) * 4);
  float sum = 0.f;
  for (int j = 0; j <= i; ++j) {
    char* tbj = tb0 + (size_t)j * 65536;
    const float* tp = (const float*)tbj + r * 128 + l * 2;
    const float v0 = tp[0], v1 = tp[1];                // read (wave-lockstep)
    const int col = j * 128 + l * 2;
    const float p0 = (col < len) ? __expf(v0 - mx) : 0.f;
    const float p1 = (col + 1 < len) ? __expf(v1 - mx) : 0.f;
    sum += p0 + p1;
    half2v hv; hv[0] = (_Float16)p0; hv[1] = (_Float16)p1;
    *(half2v*)(tbj + pb) = hv;                         // write (same row only)
  }
#pragma unroll
  for (int off = 1; off < 64; off <<= 1) sum += __shfl_xor(sum, off);
  if (l == 0) lrow[b * 2048 + m] = sum;
}

// ---- PV: O = P*V (via VhT), 128^2 tile, gload_lds, balanced pairing ----
__global__ __launch_bounds__(256, 3) void pv(const float* __restrict__ Sp,
                                             const _Float16* __restrict__ VhT,
                                             const float* __restrict__ lrow,
                                             float* __restrict__ O) {
  __shared__ __align__(16) char As[16384];   // P [128 q][64 kv] f16
  __shared__ __align__(16) char Bs[16384];   // VhT [128 d][64 kv] f16
  __shared__ float Lsh[128];
  const int tid = threadIdx.x;
  const int w = tid >> 6, l = tid & 63, l15 = l & 15, hi = l >> 4;
  const int wr = (w >> 1) * 64, wc = (w & 1) * 64;

  const int b = (int)(blockIdx.x & 3), t = (int)(blockIdx.x >> 2);
  const int r_ = t >> 3;
  const int i = (r_ < 8) ? (15 - r_) : (r_ - 8);   // pair sums constant
  const int nc = t & 7;
  const int ns = (i + 1) * 2;

  const char* Pbase = (const char*)(Sp + (size_t)(b * NTILE + ((i * (i + 1)) >> 1)) * TILE_ELEMS);
  const int arow = w * 32 + (l >> 3);
  const _Float16* Bsrc = VhT + ((size_t)(b * D_ + nc * 128 + arow)) * T_ + (l & 7) * 8;
  char* Adst = As + w * 4096;
  char* Bdst = Bs + w * 4096;
  if (tid < 128) Lsh[tid] = lrow[b * 2048 + i * 128 + tid];

  floatx4 acc[4][4];
#pragma unroll
  for (int mi = 0; mi < 4; ++mi)
#pragma unroll
    for (int ni = 0; ni < 4; ++ni) acc[mi][ni] = (floatx4){0.f, 0.f, 0.f, 0.f};

  for (int s = 0; s < ns; ++s) {
#pragma unroll
    for (int q = 0; q < 4; ++q)
      gl16(Pbase + (size_t)(s >> 1) * 65536 + (size_t)(arow + q * 8) * 512 +
               (s & 1) * 128 + (l & 7) * 16,
           Adst + q * 1024);
#pragma unroll
    for (int q = 0; q < 4; ++q)
      gl16(Bsrc + (size_t)q * 8 * T_ + s * 64, Bdst + q * 1024);
    __syncthreads();
#pragma unroll
    for (int s32 = 0; s32 < 2; ++s32) {
      half8 af[4], bb[4];
#pragma unroll
      for (int mi = 0; mi < 4; ++mi) {
        const int row = wr + mi * 16 + l15;
        af[mi] = *(const half8*)(As + row * 128 + ((((s32 << 2) | hi) ^ (row & 7)) << 4));
      }
#pragma unroll
      for (int ni = 0; ni < 4; ++ni) {
        const int row = wc + ni * 16 + l15;
        bb[ni] = *(const half8*)(Bs + row * 128 + ((((s32 << 2) | hi) ^ (row & 7)) << 4));
      }
#pragma unroll
      for (int mi = 0; mi < 4; ++mi)
#pragma unroll
        for (int ni = 0; ni < 4; ++ni)
          acc[mi][ni] = MFMA16(af[mi], bb[ni], acc[mi][ni]);
    }
    __syncthreads();
  }

  float* Ob = O + ((size_t)b * T_ + i * 128) * D_ + nc * 128;
#pragma unroll
  for (int mi = 0; mi < 4; ++mi)
#pragma unroll
    for (int r = 0; r < 4; ++r) {
      const int rl = wr + mi * 16 + 4 * hi + r;
      const float inv = 1.0f / Lsh[rl];
#pragma unroll
      for (int ni = 0; ni < 4; ++ni)
        Ob[(size_t)rl * D_ + wc + ni * 16 + l15] = acc[mi][ni][r] * inv;
    }
}

// ---- fallback (ws too small — slow but correct) ----
__global__ __launch_bounds__(256) void attn_fb(const float* __restrict__ Q,
                                               const float* __restrict__ V,
                                               float* __restrict__ O) {
  __shared__ float sc[2048];
  __shared__ float red[4];
  const int b = (int)(blockIdx.x >> 11), m = (int)(blockIdx.x & 2047);
  const int tid = threadIdx.x;
  const float* Qr = Q + ((size_t)b * T_ + m) * D_;
  for (int kv = tid; kv <= m; kv += 256) {
    const float* Vr = V + ((size_t)b * T_ + kv) * D_;
    float s = 0.f;
    for (int d = 0; d < D_; d += 4) {
      floatx4 q4 = *(const floatx4*)(Qr + d), v4 = *(const floatx4*)(Vr + d);
      s += q4[0] * v4[0] + q4[1] * v4[1] + q4[2] * v4[2] + q4[3] * v4[3];
    }
    sc[kv] = s;
  }
  __syncthreads();
  float mx = -1e30f;
  for (int kv = tid; kv <= m; kv += 256) mx = fmaxf(mx, sc[kv]);
#pragma unroll
  for (int off = 1; off < 64; off <<= 1) mx = fmaxf(mx, __shfl_xor(mx, off));
  if ((tid & 63) == 0) red[tid >> 6] = mx;
  __syncthreads();
  mx = fmaxf(fmaxf(red[0], red[1]), fmaxf(red[2], red[3]));
  __syncthreads();
  float sum = 0.f;
  for (int kv = tid; kv <= m; kv += 256) { float p = __expf(sc[kv] - mx); sc[kv] = p; sum += p; }
#pragma unroll
  for (int off = 1; off < 64; off <<= 1) sum += __shfl_xor(sum, off);
  __syncthreads();
  if ((tid & 63) == 0) red[tid >> 6] = sum;
  __syncthreads();
  const float inv = 1.0f / (red[0] + red[1] + red[2] + red[3]);
  float* Or = O + ((size_t)b * T_ + m) * D_;
  const int d = tid * 4;
  floatx4 o = {0.f, 0.f, 0.f, 0.f};
  for (int kv = 0; kv <= m; ++kv) {
    const float p = sc[kv];
    const floatx4 v4 = *(const floatx4*)(V + ((size_t)b * T_ + kv) * D_ + d);
    o[0] += p * v4[0]; o[1] += p * v4[1]; o[2] += p * v4[2]; o[3] += p * v4[3];
  }
  o[0] *= inv; o[1] *= inv; o[2] *= inv; o[3] *= inv;
  *(floatx4*)(Or + d) = o;
}

extern "C" void kernel_launch(void* const* d_in, const int* in_sizes, int n_in,
                              void* d_out, int out_size, void* d_ws, size_t ws_size,
                              hipStream_t stream) {
  const float* q = (const float*)d_in[0];
  const float* v = (const float*)d_in[1];
  float* out = (float*)d_out;

  const size_t OFF_S = 16777216;                                    // Qh/VhT slot (reused)
  const size_t OFF_L = OFF_S + (size_t)NB * NTILE * TILE_ELEMS * 4; // 52,428,800
  const size_t NEED = OFF_L + (size_t)NB * 2048 * 4;                // ~52.5 MB

  if (ws_size >= NEED) {
    _Float16* fh = (_Float16*)d_ws;                 // Qh, later VhT
    float* Sp = (float*)((char*)d_ws + OFF_S);
    float* lr = (float*)((char*)d_ws + OFF_L);
    cast_q<<<dim3(4096), dim3(256), 0, stream>>>(q, fh);
    sgemm<<<dim3(NB * NTILE), dim3(256), 0, stream>>>(fh, v, Sp);
    smax<<<dim3(2048), dim3(256), 0, stream>>>(Sp, lr);
    build_vt<<<dim3(2048), dim3(256), 0, stream>>>(v, fh);   // Qh dead -> VhT
    pv<<<dim3(512), dim3(256), 0, stream>>>(Sp, fh, lr, out);
  } else {
    attn_fb<<<dim3(NB * T_), dim3(256), 0, stream>>>(q, v, out);
  }
}